// Round 1
// baseline (405.617 us; speedup 1.0000x reference)
//
#include <hip/hip_runtime.h>
#include <cstdint>

#define NN 32768
#define EE 524288
#define E2T (EE + NN)   // 557056 edges incl self loops
#define HID 128

__device__ __forceinline__ float lrelu(float v) { return v > 0.0f ? v : 0.2f * v; }

// ---------------------------------------------------------------------------
// One dense layer: c = relu(a @ W + bias), a/c are [32][128] in LDS, W [128][128] in LDS.
// 256 threads: thread t handles rows {r8, r8+8, r8+16, r8+24} x cols [cg, cg+4)
// ---------------------------------------------------------------------------
__device__ __forceinline__ void gemm_layer(const float* a, float* c, const float* w,
                                           const float* bias, int t)
{
  const int cg = (t & 31) * 4;
  const int r8 = t >> 5;
  float4 acc[4] = {{0,0,0,0},{0,0,0,0},{0,0,0,0},{0,0,0,0}};
  #pragma unroll 4
  for (int k = 0; k < HID; ++k) {
    float4 wv = *(const float4*)&w[k * HID + cg];
    float xr0 = a[(r8     ) * HID + k];
    float xr1 = a[(r8 +  8) * HID + k];
    float xr2 = a[(r8 + 16) * HID + k];
    float xr3 = a[(r8 + 24) * HID + k];
    acc[0].x = fmaf(xr0, wv.x, acc[0].x); acc[0].y = fmaf(xr0, wv.y, acc[0].y);
    acc[0].z = fmaf(xr0, wv.z, acc[0].z); acc[0].w = fmaf(xr0, wv.w, acc[0].w);
    acc[1].x = fmaf(xr1, wv.x, acc[1].x); acc[1].y = fmaf(xr1, wv.y, acc[1].y);
    acc[1].z = fmaf(xr1, wv.z, acc[1].z); acc[1].w = fmaf(xr1, wv.w, acc[1].w);
    acc[2].x = fmaf(xr2, wv.x, acc[2].x); acc[2].y = fmaf(xr2, wv.y, acc[2].y);
    acc[2].z = fmaf(xr2, wv.z, acc[2].z); acc[2].w = fmaf(xr2, wv.w, acc[2].w);
    acc[3].x = fmaf(xr3, wv.x, acc[3].x); acc[3].y = fmaf(xr3, wv.y, acc[3].y);
    acc[3].z = fmaf(xr3, wv.z, acc[3].z); acc[3].w = fmaf(xr3, wv.w, acc[3].w);
  }
  float4 bb = *(const float4*)&bias[cg];
  #pragma unroll
  for (int i = 0; i < 4; ++i) {
    float4 v = acc[i];
    v.x = fmaxf(v.x + bb.x, 0.0f);
    v.y = fmaxf(v.y + bb.y, 0.0f);
    v.z = fmaxf(v.z + bb.z, 0.0f);
    v.w = fmaxf(v.w + bb.w, 0.0f);
    *(float4*)&c[(r8 + 8 * i) * HID + cg] = v;
  }
}

// ---------------------------------------------------------------------------
// MLP: h = LN(relu(relu(x@W1+b1)@W2+b2)) * g + b    (32 rows / block)
// ---------------------------------------------------------------------------
__global__ __launch_bounds__(256) void k_mlp(
    const float* __restrict__ x, const float* __restrict__ w1,
    const float* __restrict__ b1, const float* __restrict__ w2,
    const float* __restrict__ b2, const float* __restrict__ ln_g,
    const float* __restrict__ ln_b, float* __restrict__ hout)
{
  __shared__ float w_ls[HID * HID];   // 64 KB, reused for W1 then W2
  __shared__ float a_ls[32 * HID];    // 16 KB
  __shared__ float c_ls[32 * HID];    // 16 KB
  const int t = threadIdx.x;
  const int row0 = blockIdx.x * 32;

  for (int i = 4 * t; i < HID * HID; i += 1024)
    *(float4*)&w_ls[i] = *(const float4*)&w1[i];
  for (int i = 4 * t; i < 32 * HID; i += 1024)
    *(float4*)&a_ls[i] = *(const float4*)&x[(size_t)row0 * HID + i];
  __syncthreads();

  gemm_layer(a_ls, c_ls, w_ls, b1, t);   // layer 1 -> c_ls
  __syncthreads();
  for (int i = 4 * t; i < HID * HID; i += 1024)
    *(float4*)&w_ls[i] = *(const float4*)&w2[i];
  __syncthreads();
  gemm_layer(c_ls, a_ls, w_ls, b2, t);   // layer 2 -> a_ls
  __syncthreads();

  // LayerNorm: wave handles 8 rows, lane holds 2 channels
  const int lane = t & 63;
  const int wv = t >> 6;
  for (int i = 0; i < 8; ++i) {
    const int r = wv * 8 + i;
    float v0 = a_ls[r * HID + 2 * lane];
    float v1 = a_ls[r * HID + 2 * lane + 1];
    float s = v0 + v1, q = v0 * v0 + v1 * v1;
    #pragma unroll
    for (int off = 1; off < 64; off <<= 1) {
      s += __shfl_xor(s, off);
      q += __shfl_xor(q, off);
    }
    float mu = s * (1.0f / 128.0f);
    float var = q * (1.0f / 128.0f) - mu * mu;
    float rs = rsqrtf(var + 1e-5f);
    float2 o;
    o.x = (v0 - mu) * rs * ln_g[2 * lane]     + ln_b[2 * lane];
    o.y = (v1 - mu) * rs * ln_g[2 * lane + 1] + ln_b[2 * lane + 1];
    *(float2*)&hout[(size_t)(row0 + r) * HID + 2 * lane] = o;
  }
}

// ---------------------------------------------------------------------------
// xh = h @ w_lin  (h [N,128], w_lin [128,512]); block = 32 rows x 128-col chunk
// ---------------------------------------------------------------------------
__global__ __launch_bounds__(256) void k_lin(
    const float* __restrict__ h, const float* __restrict__ w_lin,
    float* __restrict__ xh)
{
  __shared__ float w_ls[HID * HID];   // 64 KB (one 128-col chunk)
  __shared__ float a_ls[32 * HID];    // 16 KB
  const int t = threadIdx.x;
  const int row0 = (blockIdx.x >> 2) * 32;
  const int cc = blockIdx.x & 3;

  for (int i = 4 * t; i < HID * HID; i += 1024) {
    int k = i >> 7, j = i & 127;
    *(float4*)&w_ls[i] = *(const float4*)&w_lin[(size_t)k * 512 + cc * 128 + j];
  }
  for (int i = 4 * t; i < 32 * HID; i += 1024)
    *(float4*)&a_ls[i] = *(const float4*)&h[(size_t)row0 * HID + i];
  __syncthreads();

  const int cg = (t & 31) * 4;
  const int r8 = t >> 5;
  float4 acc[4] = {{0,0,0,0},{0,0,0,0},{0,0,0,0},{0,0,0,0}};
  #pragma unroll 4
  for (int k = 0; k < HID; ++k) {
    float4 wv = *(const float4*)&w_ls[k * HID + cg];
    float xr0 = a_ls[(r8     ) * HID + k];
    float xr1 = a_ls[(r8 +  8) * HID + k];
    float xr2 = a_ls[(r8 + 16) * HID + k];
    float xr3 = a_ls[(r8 + 24) * HID + k];
    acc[0].x = fmaf(xr0, wv.x, acc[0].x); acc[0].y = fmaf(xr0, wv.y, acc[0].y);
    acc[0].z = fmaf(xr0, wv.z, acc[0].z); acc[0].w = fmaf(xr0, wv.w, acc[0].w);
    acc[1].x = fmaf(xr1, wv.x, acc[1].x); acc[1].y = fmaf(xr1, wv.y, acc[1].y);
    acc[1].z = fmaf(xr1, wv.z, acc[1].z); acc[1].w = fmaf(xr1, wv.w, acc[1].w);
    acc[2].x = fmaf(xr2, wv.x, acc[2].x); acc[2].y = fmaf(xr2, wv.y, acc[2].y);
    acc[2].z = fmaf(xr2, wv.z, acc[2].z); acc[2].w = fmaf(xr2, wv.w, acc[2].w);
    acc[3].x = fmaf(xr3, wv.x, acc[3].x); acc[3].y = fmaf(xr3, wv.y, acc[3].y);
    acc[3].z = fmaf(xr3, wv.z, acc[3].z); acc[3].w = fmaf(xr3, wv.w, acc[3].w);
  }
  #pragma unroll
  for (int i = 0; i < 4; ++i)
    *(float4*)&xh[(size_t)(row0 + r8 + 8 * i) * 512 + cc * 128 + cg] = acc[i];
}

// ---------------------------------------------------------------------------
// attention logit coefficients: a_src[n,h] = <xh[n,h,:], att_src[h,:]>, same a_dst
// one wave per node
// ---------------------------------------------------------------------------
__global__ __launch_bounds__(256) void k_att(
    const float* __restrict__ xh, const float* __restrict__ att_s,
    const float* __restrict__ att_d, float* __restrict__ a_src,
    float* __restrict__ a_dst)
{
  const int lane = threadIdx.x & 63;
  const int n = blockIdx.x * 4 + (threadIdx.x >> 6);
  const float* xr = &xh[(size_t)n * 512];
  float4 xa = *(const float4*)&xr[4 * lane];
  float4 xb = *(const float4*)&xr[256 + 4 * lane];
  float4 sa = *(const float4*)&att_s[4 * lane];
  float4 sb = *(const float4*)&att_s[256 + 4 * lane];
  float4 da = *(const float4*)&att_d[4 * lane];
  float4 db = *(const float4*)&att_d[256 + 4 * lane];
  float ps1 = xa.x*sa.x + xa.y*sa.y + xa.z*sa.z + xa.w*sa.w;
  float ps2 = xb.x*sb.x + xb.y*sb.y + xb.z*sb.z + xb.w*sb.w;
  float pd1 = xa.x*da.x + xa.y*da.y + xa.z*da.z + xa.w*da.w;
  float pd2 = xb.x*db.x + xb.y*db.y + xb.z*db.z + xb.w*db.w;
  #pragma unroll
  for (int off = 1; off < 32; off <<= 1) {
    ps1 += __shfl_xor(ps1, off); ps2 += __shfl_xor(ps2, off);
    pd1 += __shfl_xor(pd1, off); pd2 += __shfl_xor(pd2, off);
  }
  if ((lane & 31) == 0) {
    int hh = lane >> 5;   // 0 or 1
    a_src[n * 4 + hh]     = ps1;
    a_src[n * 4 + 2 + hh] = ps2;
    a_dst[n * 4 + hh]     = pd1;
    a_dst[n * 4 + 2 + hh] = pd2;
  }
}

// ---------------------------------------------------------------------------
// CSR build: histogram -> scan -> scatter (sorted by dst)
// ---------------------------------------------------------------------------
__global__ void k_hist(const int* __restrict__ ei, int* __restrict__ count)
{
  int i = blockIdx.x * 256 + threadIdx.x;
  if (i >= E2T) return;
  int dst = (i < EE) ? ei[EE + i] : (i - EE);
  atomicAdd(&count[dst], 1);
}

__global__ __launch_bounds__(256) void k_scan(const int* __restrict__ count,
                                              int* __restrict__ offsets,
                                              int* __restrict__ cursor)
{
  __shared__ int wtot[4];
  const int t = threadIdx.x;
  const int base = t * (NN / 256);   // 128 counts per thread
  int s = 0;
  for (int k = 0; k < NN / 256; ++k) s += count[base + k];
  const int lane = t & 63, w = t >> 6;
  int v = s;
  #pragma unroll
  for (int off = 1; off < 64; off <<= 1) {
    int u = __shfl_up(v, off);
    if (lane >= off) v += u;
  }
  if (lane == 63) wtot[w] = v;
  __syncthreads();
  int wpre = 0;
  for (int i = 0; i < w; ++i) wpre += wtot[i];
  int run = v + wpre - s;   // exclusive prefix of this thread's chunk
  for (int k = 0; k < NN / 256; ++k) {
    offsets[base + k] = run;
    cursor[base + k] = run;
    run += count[base + k];
  }
  if (t == 255) offsets[NN] = run;
}

__global__ void k_scatter(const int* __restrict__ ei, int* __restrict__ cursor,
                          int* __restrict__ srcs)
{
  int i = blockIdx.x * 256 + threadIdx.x;
  if (i >= E2T) return;
  int s, d;
  if (i < EE) { s = ei[i]; d = ei[EE + i]; }
  else        { s = i - EE; d = s; }
  int pos = atomicAdd(&cursor[d], 1);
  srcs[pos] = s;
}

// ---------------------------------------------------------------------------
// GAT aggregation: one wave per dst node. Pass 1: per-head max. Pass 2 (chunks
// of 64 edges): exp, denom partials, and channel-parallel weighted accumulation.
// Lane owns channels f in {4*lane..4*lane+3} (head lane/32) and
// {256+4*lane..+3} (head 2+lane/32); heads combined via shfl_xor(,32).
// ---------------------------------------------------------------------------
__global__ __launch_bounds__(256) void k_gat(
    const float* __restrict__ xh, const float* __restrict__ a_src,
    const float* __restrict__ a_dst, const int* __restrict__ offsets,
    const int* __restrict__ srcs, const float* __restrict__ bias,
    float* __restrict__ out)
{
  __shared__ float2 ex_ls[4][64][2];
  __shared__ int src_ls[4][64];
  const int lane = threadIdx.x & 63;
  const int w = threadIdx.x >> 6;
  const int n = blockIdx.x * 4 + w;
  const float4 adn = *(const float4*)&a_dst[n * 4];
  const int beg = offsets[n];
  const int deg = offsets[n + 1] - beg;

  // pass 1: per-head max over incoming edges
  float m0 = -INFINITY, m1 = -INFINITY, m2 = -INFINITY, m3 = -INFINITY;
  for (int j = lane; j < deg; j += 64) {
    int s = srcs[beg + j];
    float4 as = *(const float4*)&a_src[s * 4];
    m0 = fmaxf(m0, lrelu(as.x + adn.x));
    m1 = fmaxf(m1, lrelu(as.y + adn.y));
    m2 = fmaxf(m2, lrelu(as.z + adn.z));
    m3 = fmaxf(m3, lrelu(as.w + adn.w));
  }
  #pragma unroll
  for (int off = 1; off < 64; off <<= 1) {
    m0 = fmaxf(m0, __shfl_xor(m0, off));
    m1 = fmaxf(m1, __shfl_xor(m1, off));
    m2 = fmaxf(m2, __shfl_xor(m2, off));
    m3 = fmaxf(m3, __shfl_xor(m3, off));
  }

  const int h1 = lane >> 5;
  const int o1 = 4 * lane;
  const int o2 = 256 + 4 * lane;
  float4 acc1 = {0,0,0,0}, acc2 = {0,0,0,0};
  float d0 = 0, d1 = 0, d2 = 0, d3 = 0;

  for (int j0 = 0; j0 < deg; j0 += 64) {
    int j = j0 + lane;
    if (j < deg) {
      int s = srcs[beg + j];
      float4 as = *(const float4*)&a_src[s * 4];
      float x0 = expf(lrelu(as.x + adn.x) - m0);
      float x1 = expf(lrelu(as.y + adn.y) - m1);
      float x2 = expf(lrelu(as.z + adn.z) - m2);
      float x3 = expf(lrelu(as.w + adn.w) - m3);
      d0 += x0; d1 += x1; d2 += x2; d3 += x3;
      ex_ls[w][lane][0] = make_float2(x0, x2);
      ex_ls[w][lane][1] = make_float2(x1, x3);
      src_ls[w][lane] = s;
    }
    __builtin_amdgcn_wave_barrier();   // wave-internal LDS ordering (no block barrier: waves diverge)
    const int cnt = min(64, deg - j0);
    #pragma unroll 2
    for (int jj = 0; jj < cnt; ++jj) {
      int s = src_ls[w][jj];
      float2 ep = ex_ls[w][jj][h1];
      const float* xr = &xh[(size_t)s * 512];
      float4 x1v = *(const float4*)&xr[o1];
      float4 x2v = *(const float4*)&xr[o2];
      acc1.x = fmaf(ep.x, x1v.x, acc1.x); acc1.y = fmaf(ep.x, x1v.y, acc1.y);
      acc1.z = fmaf(ep.x, x1v.z, acc1.z); acc1.w = fmaf(ep.x, x1v.w, acc1.w);
      acc2.x = fmaf(ep.y, x2v.x, acc2.x); acc2.y = fmaf(ep.y, x2v.y, acc2.y);
      acc2.z = fmaf(ep.y, x2v.z, acc2.z); acc2.w = fmaf(ep.y, x2v.w, acc2.w);
    }
    __builtin_amdgcn_wave_barrier();
  }

  #pragma unroll
  for (int off = 1; off < 64; off <<= 1) {
    d0 += __shfl_xor(d0, off); d1 += __shfl_xor(d1, off);
    d2 += __shfl_xor(d2, off); d3 += __shfl_xor(d3, off);
  }
  float da = (h1 ? d1 : d0) + 1e-16f;
  float db = (h1 ? d3 : d2) + 1e-16f;
  float t0 = acc1.x / da + acc2.x / db;
  float t1 = acc1.y / da + acc2.y / db;
  float t2 = acc1.z / da + acc2.z / db;
  float t3 = acc1.w / da + acc2.w / db;
  t0 += __shfl_xor(t0, 32);
  t1 += __shfl_xor(t1, 32);
  t2 += __shfl_xor(t2, 32);
  t3 += __shfl_xor(t3, 32);
  if (lane < 32) {
    float4 bv = *(const float4*)&bias[4 * lane];
    float4 o;
    o.x = 0.25f * t0 + bv.x;
    o.y = 0.25f * t1 + bv.y;
    o.z = 0.25f * t2 + bv.z;
    o.w = 0.25f * t3 + bv.w;
    *(float4*)&out[(size_t)n * HID + 4 * lane] = o;
  }
}

// ---------------------------------------------------------------------------
extern "C" void kernel_launch(void* const* d_in, const int* in_sizes, int n_in,
                              void* d_out, int out_size, void* d_ws, size_t ws_size,
                              hipStream_t stream)
{
  const float* x     = (const float*)d_in[0];
  const int*   ei    = (const int*)  d_in[1];
  const float* w1    = (const float*)d_in[2];
  const float* b1    = (const float*)d_in[3];
  const float* w2    = (const float*)d_in[4];
  const float* b2    = (const float*)d_in[5];
  const float* ln_g  = (const float*)d_in[6];
  const float* ln_b  = (const float*)d_in[7];
  const float* w_lin = (const float*)d_in[8];
  const float* att_s = (const float*)d_in[9];
  const float* att_d = (const float*)d_in[10];
  const float* bias  = (const float*)d_in[11];
  float* out = (float*)d_out;

  char* ws = (char*)d_ws;
  size_t off = 0;
  auto alloc = [&](size_t bytes) -> char* {
    char* p = ws + off;
    off += (bytes + 255) & ~(size_t)255;
    return p;
  };
  float* h      = (float*)alloc((size_t)NN * HID * 4);   // 16 MB
  float* xh     = (float*)alloc((size_t)NN * 512 * 4);   // 64 MB
  float* a_src  = (float*)alloc((size_t)NN * 4 * 4);
  float* a_dst  = (float*)alloc((size_t)NN * 4 * 4);
  int* count    = (int*)alloc((size_t)NN * 4);
  int* offsets  = (int*)alloc((size_t)(NN + 1) * 4);
  int* cursor   = (int*)alloc((size_t)NN * 4);
  int* srcs     = (int*)alloc((size_t)E2T * 4);
  if (off > ws_size) return;   // workspace too small: fail visibly (poisoned out)

  hipMemsetAsync(count, 0, (size_t)NN * 4, stream);

  k_mlp<<<NN / 32, 256, 0, stream>>>(x, w1, b1, w2, b2, ln_g, ln_b, h);
  k_lin<<<(NN / 32) * 4, 256, 0, stream>>>(h, w_lin, xh);
  k_att<<<NN / 4, 256, 0, stream>>>(xh, att_s, att_d, a_src, a_dst);
  k_hist<<<(E2T + 255) / 256, 256, 0, stream>>>(ei, count);
  k_scan<<<1, 256, 0, stream>>>(count, offsets, cursor);
  k_scatter<<<(E2T + 255) / 256, 256, 0, stream>>>(ei, cursor, srcs);
  k_gat<<<NN / 4, 256, 0, stream>>>(xh, a_src, a_dst, offsets, srcs, bias, out);
}

// Round 2
// 263.098 us; speedup vs baseline: 1.5417x; 1.5417x over previous
//
#include <hip/hip_runtime.h>
#include <cstdint>

#define NN 32768
#define EE 524288
#define E2T (EE + NN)   // 557056 edges incl self loops
#define HID 128

__device__ __forceinline__ float lrelu(float v) { return v > 0.0f ? v : 0.2f * v; }

// round-to-nearest-even f32 -> bf16 (values are finite here)
__device__ __forceinline__ unsigned short f2bf(float f) {
  unsigned int u = __float_as_uint(f);
  return (unsigned short)((u + 0x7fffu + ((u >> 16) & 1u)) >> 16);
}
#define BF_LO(u) __uint_as_float((u) << 16)
#define BF_HI(u) __uint_as_float((u) & 0xffff0000u)

// ---------------------------------------------------------------------------
// 64-row x 128-col GEMM tile out of LDS. 512 threads: thread t owns rows
// {r16, r16+16, r16+32, r16+48} x cols [cg, cg+4). k-blocked by 4 so all LDS
// reads are b128 (a-reads broadcast within 32-lane groups: free).
// ---------------------------------------------------------------------------
__device__ __forceinline__ void gemm64(const float* __restrict__ a,
                                       const float* __restrict__ w,
                                       int r16, int cg, float4 acc[4])
{
  acc[0] = acc[1] = acc[2] = acc[3] = make_float4(0, 0, 0, 0);
  for (int k4 = 0; k4 < 32; ++k4) {
    float4 xa = *(const float4*)&a[(r16     ) * HID + 4 * k4];
    float4 xb = *(const float4*)&a[(r16 + 16) * HID + 4 * k4];
    float4 xc = *(const float4*)&a[(r16 + 32) * HID + 4 * k4];
    float4 xd = *(const float4*)&a[(r16 + 48) * HID + 4 * k4];
    #pragma unroll
    for (int kk = 0; kk < 4; ++kk) {
      float4 wv = *(const float4*)&w[(4 * k4 + kk) * HID + cg];
      float f0 = ((const float*)&xa)[kk];
      float f1 = ((const float*)&xb)[kk];
      float f2 = ((const float*)&xc)[kk];
      float f3 = ((const float*)&xd)[kk];
      acc[0].x = fmaf(f0, wv.x, acc[0].x); acc[0].y = fmaf(f0, wv.y, acc[0].y);
      acc[0].z = fmaf(f0, wv.z, acc[0].z); acc[0].w = fmaf(f0, wv.w, acc[0].w);
      acc[1].x = fmaf(f1, wv.x, acc[1].x); acc[1].y = fmaf(f1, wv.y, acc[1].y);
      acc[1].z = fmaf(f1, wv.z, acc[1].z); acc[1].w = fmaf(f1, wv.w, acc[1].w);
      acc[2].x = fmaf(f2, wv.x, acc[2].x); acc[2].y = fmaf(f2, wv.y, acc[2].y);
      acc[2].z = fmaf(f2, wv.z, acc[2].z); acc[2].w = fmaf(f2, wv.w, acc[2].w);
      acc[3].x = fmaf(f3, wv.x, acc[3].x); acc[3].y = fmaf(f3, wv.y, acc[3].y);
      acc[3].z = fmaf(f3, wv.z, acc[3].z); acc[3].w = fmaf(f3, wv.w, acc[3].w);
    }
  }
}

// ---------------------------------------------------------------------------
// Fused: h = LN(relu(relu(x@W1+b1)@W2+b2)); xh = bf16(h @ w_lin);
// a_src/a_dst = per-head <xh_row, att>. 64 rows / block, 512 threads, 128KB LDS.
// ---------------------------------------------------------------------------
__global__ __launch_bounds__(512) void k_mlp(
    const float* __restrict__ x, const float* __restrict__ w1,
    const float* __restrict__ b1, const float* __restrict__ w2,
    const float* __restrict__ b2, const float* __restrict__ ln_g,
    const float* __restrict__ ln_b, const float* __restrict__ w_lin,
    const float* __restrict__ att_s, const float* __restrict__ att_d,
    unsigned short* __restrict__ xh, float* __restrict__ a_src,
    float* __restrict__ a_dst)
{
  __shared__ float w_ls[HID * HID];   // 64 KB (W1, then W2, then w_lin chunks)
  __shared__ float a_ls[64 * HID];    // 32 KB
  __shared__ float c_ls[64 * HID];    // 32 KB
  const int t = threadIdx.x;
  const int row0 = blockIdx.x * 64;
  const int cg = (t & 31) * 4;
  const int r16 = t >> 5;
  float4 acc[4];

  for (int i = 4 * t; i < HID * HID; i += 2048)
    *(float4*)&w_ls[i] = *(const float4*)&w1[i];
  for (int i = 4 * t; i < 64 * HID; i += 2048)
    *(float4*)&a_ls[i] = *(const float4*)&x[(size_t)row0 * HID + i];
  __syncthreads();

  // layer 1: a -> c
  gemm64(a_ls, w_ls, r16, cg, acc);
  {
    float4 bb = *(const float4*)&b1[cg];
    #pragma unroll
    for (int i = 0; i < 4; ++i) {
      float4 v = acc[i];
      v.x = fmaxf(v.x + bb.x, 0.0f); v.y = fmaxf(v.y + bb.y, 0.0f);
      v.z = fmaxf(v.z + bb.z, 0.0f); v.w = fmaxf(v.w + bb.w, 0.0f);
      *(float4*)&c_ls[(r16 + 16 * i) * HID + cg] = v;
    }
  }
  __syncthreads();
  for (int i = 4 * t; i < HID * HID; i += 2048)
    *(float4*)&w_ls[i] = *(const float4*)&w2[i];
  __syncthreads();

  // layer 2: c -> a
  gemm64(c_ls, w_ls, r16, cg, acc);
  {
    float4 bb = *(const float4*)&b2[cg];
    #pragma unroll
    for (int i = 0; i < 4; ++i) {
      float4 v = acc[i];
      v.x = fmaxf(v.x + bb.x, 0.0f); v.y = fmaxf(v.y + bb.y, 0.0f);
      v.z = fmaxf(v.z + bb.z, 0.0f); v.w = fmaxf(v.w + bb.w, 0.0f);
      *(float4*)&a_ls[(r16 + 16 * i) * HID + cg] = v;
    }
  }
  __syncthreads();

  // LayerNorm in place on a_ls: wave handles 8 rows, lane holds 2 channels
  {
    const int lane = t & 63;
    const int wv8 = t >> 6;
    float g0 = ln_g[2 * lane], g1 = ln_g[2 * lane + 1];
    float bb0 = ln_b[2 * lane], bb1 = ln_b[2 * lane + 1];
    for (int i = 0; i < 8; ++i) {
      const int r = wv8 * 8 + i;
      float v0 = a_ls[r * HID + 2 * lane];
      float v1 = a_ls[r * HID + 2 * lane + 1];
      float s = v0 + v1, q = v0 * v0 + v1 * v1;
      #pragma unroll
      for (int off = 1; off < 64; off <<= 1) {
        s += __shfl_xor(s, off);
        q += __shfl_xor(q, off);
      }
      float mu = s * (1.0f / 128.0f);
      float var = q * (1.0f / 128.0f) - mu * mu;
      float rs = rsqrtf(var + 1e-5f);
      a_ls[r * HID + 2 * lane]     = (v0 - mu) * rs * g0 + bb0;
      a_ls[r * HID + 2 * lane + 1] = (v1 - mu) * rs * g1 + bb1;
    }
  }
  __syncthreads();

  // head chunks of w_lin: xh (bf16) + attention coefficients
  for (int cc = 0; cc < 4; ++cc) {
    for (int i = 4 * t; i < HID * HID; i += 2048) {
      int k = i >> 7, j = i & 127;
      *(float4*)&w_ls[i] = *(const float4*)&w_lin[(size_t)k * 512 + cc * HID + j];
    }
    __syncthreads();
    gemm64(a_ls, w_ls, r16, cg, acc);
    float4 asv = *(const float4*)&att_s[cc * HID + cg];
    float4 adv = *(const float4*)&att_d[cc * HID + cg];
    #pragma unroll
    for (int i = 0; i < 4; ++i) {
      const int row = row0 + r16 + 16 * i;
      ushort4 u;
      u.x = f2bf(acc[i].x); u.y = f2bf(acc[i].y);
      u.z = f2bf(acc[i].z); u.w = f2bf(acc[i].w);
      *(ushort4*)&xh[(size_t)row * 512 + cc * HID + cg] = u;
      float ps = acc[i].x * asv.x + acc[i].y * asv.y + acc[i].z * asv.z + acc[i].w * asv.w;
      float pd = acc[i].x * adv.x + acc[i].y * adv.y + acc[i].z * adv.z + acc[i].w * adv.w;
      #pragma unroll
      for (int off = 1; off < 32; off <<= 1) {
        ps += __shfl_xor(ps, off);
        pd += __shfl_xor(pd, off);
      }
      if ((t & 31) == 0) {
        a_src[row * 4 + cc] = ps;
        a_dst[row * 4 + cc] = pd;
      }
    }
    __syncthreads();
  }
}

// ---------------------------------------------------------------------------
// CSR build: histogram -> scan -> scatter (sorted by dst)
// ---------------------------------------------------------------------------
__global__ void k_hist(const int* __restrict__ ei, int* __restrict__ count)
{
  int i = blockIdx.x * 256 + threadIdx.x;
  if (i >= E2T) return;
  int dst = (i < EE) ? ei[EE + i] : (i - EE);
  atomicAdd(&count[dst], 1);
}

__global__ __launch_bounds__(256) void k_scan(const int* __restrict__ count,
                                              int* __restrict__ offsets,
                                              int* __restrict__ cursor)
{
  __shared__ int wtot[4];
  const int t = threadIdx.x;
  const int base = t * (NN / 256);   // 128 counts per thread
  int s = 0;
  for (int k = 0; k < NN / 256; ++k) s += count[base + k];
  const int lane = t & 63, w = t >> 6;
  int v = s;
  #pragma unroll
  for (int off = 1; off < 64; off <<= 1) {
    int u = __shfl_up(v, off);
    if (lane >= off) v += u;
  }
  if (lane == 63) wtot[w] = v;
  __syncthreads();
  int wpre = 0;
  for (int i = 0; i < w; ++i) wpre += wtot[i];
  int run = v + wpre - s;   // exclusive prefix of this thread's chunk
  for (int k = 0; k < NN / 256; ++k) {
    offsets[base + k] = run;
    cursor[base + k] = run;
    run += count[base + k];
  }
  if (t == 255) offsets[NN] = run;
}

__global__ void k_scatter(const int* __restrict__ ei, int* __restrict__ cursor,
                          int* __restrict__ srcs)
{
  int i = blockIdx.x * 256 + threadIdx.x;
  if (i >= E2T) return;
  int s, d;
  if (i < EE) { s = ei[i]; d = ei[EE + i]; }
  else        { s = i - EE; d = s; }
  int pos = atomicAdd(&cursor[d], 1);
  srcs[pos] = s;
}

// ---------------------------------------------------------------------------
// GAT aggregation: one wave per dst node, single pass (softmax without max
// subtraction -- shift-invariant; logits are ~N(0,2), no overflow risk).
// Lane owns 8 consecutive channels c = 8*lane..8*lane+7 of the 512 (head =
// lane>>4). Per edge: one coalesced 16B bf16 load per lane covers the row.
// Heads combined via shfl_xor(16|32); lanes 0..15 write the node's 128 floats.
// ---------------------------------------------------------------------------
__global__ __launch_bounds__(256) void k_gat(
    const unsigned short* __restrict__ xh, const float* __restrict__ a_src,
    const float* __restrict__ a_dst, const int* __restrict__ offsets,
    const int* __restrict__ srcs, const float* __restrict__ bias,
    float* __restrict__ out)
{
  __shared__ float ex_ls[4][64][4];
  __shared__ int src_ls[4][64];
  const int lane = threadIdx.x & 63;
  const int w = threadIdx.x >> 6;
  const int n = blockIdx.x * 4 + w;
  const float4 adn = *(const float4*)&a_dst[n * 4];
  const int beg = offsets[n];
  const int deg = offsets[n + 1] - beg;
  const int h1 = lane >> 4;

  float acc[8] = {0, 0, 0, 0, 0, 0, 0, 0};
  float d0 = 0, d1 = 0, d2 = 0, d3 = 0;

  for (int j0 = 0; j0 < deg; j0 += 64) {
    int j = j0 + lane;
    if (j < deg) {
      int s = srcs[beg + j];
      float4 as = *(const float4*)&a_src[s * 4];
      float x0 = __expf(lrelu(as.x + adn.x));
      float x1 = __expf(lrelu(as.y + adn.y));
      float x2 = __expf(lrelu(as.z + adn.z));
      float x3 = __expf(lrelu(as.w + adn.w));
      d0 += x0; d1 += x1; d2 += x2; d3 += x3;
      ex_ls[w][lane][0] = x0; ex_ls[w][lane][1] = x1;
      ex_ls[w][lane][2] = x2; ex_ls[w][lane][3] = x3;
      src_ls[w][lane] = s;
    }
    __builtin_amdgcn_wave_barrier();
    const int cnt = min(64, deg - j0);
    #pragma unroll 4
    for (int jj = 0; jj < cnt; ++jj) {
      int s = src_ls[w][jj];
      float e = ex_ls[w][jj][h1];
      uint4 xv = *(const uint4*)(xh + (size_t)s * 512 + 8 * lane);
      acc[0] = fmaf(e, BF_LO(xv.x), acc[0]);
      acc[1] = fmaf(e, BF_HI(xv.x), acc[1]);
      acc[2] = fmaf(e, BF_LO(xv.y), acc[2]);
      acc[3] = fmaf(e, BF_HI(xv.y), acc[3]);
      acc[4] = fmaf(e, BF_LO(xv.z), acc[4]);
      acc[5] = fmaf(e, BF_HI(xv.z), acc[5]);
      acc[6] = fmaf(e, BF_LO(xv.w), acc[6]);
      acc[7] = fmaf(e, BF_HI(xv.w), acc[7]);
    }
    __builtin_amdgcn_wave_barrier();
  }

  #pragma unroll
  for (int off = 1; off < 64; off <<= 1) {
    d0 += __shfl_xor(d0, off); d1 += __shfl_xor(d1, off);
    d2 += __shfl_xor(d2, off); d3 += __shfl_xor(d3, off);
  }
  float dh = (h1 & 2) ? ((h1 & 1) ? d3 : d2) : ((h1 & 1) ? d1 : d0);
  float inv = 1.0f / (dh + 1e-16f);
  #pragma unroll
  for (int m = 0; m < 8; ++m) {
    float r = acc[m] * inv;
    r += __shfl_xor(r, 16);
    r += __shfl_xor(r, 32);
    acc[m] = r;
  }
  if (lane < 16) {
    const int c0 = 8 * lane;
    float4 o1, o2;
    o1.x = 0.25f * acc[0] + bias[c0 + 0];
    o1.y = 0.25f * acc[1] + bias[c0 + 1];
    o1.z = 0.25f * acc[2] + bias[c0 + 2];
    o1.w = 0.25f * acc[3] + bias[c0 + 3];
    o2.x = 0.25f * acc[4] + bias[c0 + 4];
    o2.y = 0.25f * acc[5] + bias[c0 + 5];
    o2.z = 0.25f * acc[6] + bias[c0 + 6];
    o2.w = 0.25f * acc[7] + bias[c0 + 7];
    *(float4*)&out[(size_t)n * HID + c0]     = o1;
    *(float4*)&out[(size_t)n * HID + c0 + 4] = o2;
  }
}

// ---------------------------------------------------------------------------
extern "C" void kernel_launch(void* const* d_in, const int* in_sizes, int n_in,
                              void* d_out, int out_size, void* d_ws, size_t ws_size,
                              hipStream_t stream)
{
  const float* x     = (const float*)d_in[0];
  const int*   ei    = (const int*)  d_in[1];
  const float* w1    = (const float*)d_in[2];
  const float* b1    = (const float*)d_in[3];
  const float* w2    = (const float*)d_in[4];
  const float* b2    = (const float*)d_in[5];
  const float* ln_g  = (const float*)d_in[6];
  const float* ln_b  = (const float*)d_in[7];
  const float* w_lin = (const float*)d_in[8];
  const float* att_s = (const float*)d_in[9];
  const float* att_d = (const float*)d_in[10];
  const float* bias  = (const float*)d_in[11];
  float* out = (float*)d_out;

  char* ws = (char*)d_ws;
  size_t off = 0;
  auto alloc = [&](size_t bytes) -> char* {
    char* p = ws + off;
    off += (bytes + 255) & ~(size_t)255;
    return p;
  };
  unsigned short* xh = (unsigned short*)alloc((size_t)NN * 512 * 2);  // 32 MB bf16
  float* a_src  = (float*)alloc((size_t)NN * 4 * 4);
  float* a_dst  = (float*)alloc((size_t)NN * 4 * 4);
  int* count    = (int*)alloc((size_t)NN * 4);
  int* offsets  = (int*)alloc((size_t)(NN + 1) * 4);
  int* cursor   = (int*)alloc((size_t)NN * 4);
  int* srcs     = (int*)alloc((size_t)E2T * 4);
  if (off > ws_size) return;   // workspace too small: fail visibly (poisoned out)

  hipMemsetAsync(count, 0, (size_t)NN * 4, stream);

  k_hist<<<(E2T + 255) / 256, 256, 0, stream>>>(ei, count);
  k_scan<<<1, 256, 0, stream>>>(count, offsets, cursor);
  k_mlp<<<NN / 64, 512, 0, stream>>>(x, w1, b1, w2, b2, ln_g, ln_b,
                                     w_lin, att_s, att_d, xh, a_src, a_dst);
  k_scatter<<<(E2T + 255) / 256, 256, 0, stream>>>(ei, cursor, srcs);
  k_gat<<<NN / 4, 256, 0, stream>>>(xh, a_src, a_dst, offsets, srcs, bias, out);
}

// Round 3
// 203.696 us; speedup vs baseline: 1.9913x; 1.2916x over previous
//
#include <hip/hip_runtime.h>
#include <cstdint>

#define NN 32768
#define EE 524288
#define E2T (EE + NN)   // 557056 edges incl self loops
#define HID 128
#define LDSW 136        // u16 stride per LDS activation row (16B-aligned, bank-spread)

typedef __attribute__((ext_vector_type(8)))  short s16x8;
typedef __attribute__((ext_vector_type(16))) float f32x16;

union V16 { uint4 u; s16x8 s; };

__device__ __forceinline__ float lrelu(float v) { return v > 0.0f ? v : 0.2f * v; }

// round-to-nearest-even f32 -> bf16
__device__ __forceinline__ unsigned short f2bf(float f) {
  unsigned int u = __float_as_uint(f);
  return (unsigned short)((u + 0x7fffu + ((u >> 16) & 1u)) >> 16);
}
__device__ __forceinline__ float bf2f(unsigned short h) {
  return __uint_as_float(((unsigned int)h) << 16);
}
#define BF_LO(u) __uint_as_float((u) << 16)
#define BF_HI(u) __uint_as_float((u) & 0xffff0000u)

// ---------------------------------------------------------------------------
// Pre-pack weights into MFMA B-fragment order, split bf16 hi/lo planes.
// Slot s: 0-3 = W1 colfrags, 4-7 = W2 colfrags, 8-23 = w_lin (s-8 = 4*head+cf).
// Element (s, kb, lane, r) <- W[16*kb + 8*(lane>>5) + r][colbase + (lane&31)].
// Flat idx = ((s*8 + kb)*64 + lane)*8 + r. Total 24*8*64*8 = 98304 per plane.
// ---------------------------------------------------------------------------
__global__ void k_pack(const float* __restrict__ w1, const float* __restrict__ w2,
                       const float* __restrict__ wl,
                       unsigned short* __restrict__ phi, unsigned short* __restrict__ plo)
{
  int idx = blockIdx.x * 256 + threadIdx.x;   // grid covers exactly 98304
  int r  = idx & 7;
  int l  = (idx >> 3) & 63;
  int kb = (idx >> 9) & 7;
  int s  = idx >> 12;
  const float* m; int ld, n;
  if (s < 4)      { m = w1; ld = 128; n = 32 * s       + (l & 31); }
  else if (s < 8) { m = w2; ld = 128; n = 32 * (s - 4) + (l & 31); }
  else            { m = wl; ld = 512; n = 32 * (s - 8) + (l & 31); }
  int k = 16 * kb + 8 * (l >> 5) + r;
  float f = m[(size_t)k * ld + n];
  unsigned short hi = f2bf(f);
  unsigned short lo = f2bf(f - bf2f(hi));
  phi[idx] = hi;
  plo[idx] = lo;
}

// ---------------------------------------------------------------------------
// One 32x128 @ 128x(32 per wave) GEMM pass, split-bf16 3-term MFMA.
// A from LDS hi/lo planes, B fragments from pre-packed global (L2-hot).
// ---------------------------------------------------------------------------
__device__ __forceinline__ void mm_pass(int slot, int lane,
    const unsigned short* __restrict__ phi, const unsigned short* __restrict__ plo,
    const unsigned short* hi_ls, const unsigned short* lo_ls, float accv[16])
{
  f32x16 acc1 = {0,0,0,0,0,0,0,0,0,0,0,0,0,0,0,0};
  f32x16 acc2 = {0,0,0,0,0,0,0,0,0,0,0,0,0,0,0,0};
  const int arow = lane & 31;
  const int h5 = lane >> 5;
  #pragma unroll
  for (int kb = 0; kb < 8; ++kb) {
    V16 bh, bl, ah, al;
    size_t boff = ((size_t)(slot * 8 + kb) * 64 + lane) * 8;
    bh.u = *(const uint4*)&phi[boff];
    bl.u = *(const uint4*)&plo[boff];
    int aoff = arow * LDSW + 16 * kb + 8 * h5;
    ah.u = *(const uint4*)&hi_ls[aoff];
    al.u = *(const uint4*)&lo_ls[aoff];
    acc1 = __builtin_amdgcn_mfma_f32_32x32x16_bf16(ah.s, bh.s, acc1, 0, 0, 0);
    acc2 = __builtin_amdgcn_mfma_f32_32x32x16_bf16(al.s, bh.s, acc2, 0, 0, 0);
    acc2 = __builtin_amdgcn_mfma_f32_32x32x16_bf16(ah.s, bl.s, acc2, 0, 0, 0);
  }
  #pragma unroll
  for (int r = 0; r < 16; ++r) accv[r] = acc1[r] + acc2[r];
}

// ---------------------------------------------------------------------------
// Fused MLP + w_lin: 32 rows/block, 4 waves = 4 col-fragments.
// x -> LDS(hi/lo) -> relu(xW1+b1) -> relu(hW2+b2) -> LN -> xh = bf16(h@w_lin).
// ---------------------------------------------------------------------------
__global__ __launch_bounds__(256) void k_fused(
    const float* __restrict__ x, const float* __restrict__ b1,
    const float* __restrict__ b2, const float* __restrict__ ln_g,
    const float* __restrict__ ln_b, const unsigned short* __restrict__ phi,
    const unsigned short* __restrict__ plo, unsigned short* __restrict__ xh)
{
  __shared__ unsigned short hi_ls[32 * LDSW];
  __shared__ unsigned short lo_ls[32 * LDSW];
  const int t = threadIdx.x;
  const int lane = t & 63;
  const int cf = t >> 6;
  const int row0 = blockIdx.x * 32;
  const int h5 = lane >> 5;
  float acc[16];

  // stage x strip -> hi/lo planes (thread: row = t>>3, 16-col segment = t&7)
  {
    const int r = t >> 3, seg = t & 7;
    const float* src = &x[(size_t)(row0 + r) * HID + seg * 16];
    #pragma unroll
    for (int i = 0; i < 4; ++i) {
      float4 v = *(const float4*)(src + 4 * i);
      int c = seg * 16 + 4 * i;
      ushort4 h, l;
      h.x = f2bf(v.x); l.x = f2bf(v.x - bf2f(h.x));
      h.y = f2bf(v.y); l.y = f2bf(v.y - bf2f(h.y));
      h.z = f2bf(v.z); l.z = f2bf(v.z - bf2f(h.z));
      h.w = f2bf(v.w); l.w = f2bf(v.w - bf2f(h.w));
      *(ushort4*)&hi_ls[r * LDSW + c] = h;
      *(ushort4*)&lo_ls[r * LDSW + c] = l;
    }
  }
  __syncthreads();

  // ---- layer 1 ----
  mm_pass(cf, lane, phi, plo, hi_ls, lo_ls, acc);
  __syncthreads();
  {
    const int col = 32 * cf + (lane & 31);
    const float bv = b1[col];
    #pragma unroll
    for (int r = 0; r < 16; ++r) {
      int row = (r & 3) + 8 * (r >> 2) + 4 * h5;
      float v = fmaxf(acc[r] + bv, 0.0f);
      unsigned short h = f2bf(v);
      hi_ls[row * LDSW + col] = h;
      lo_ls[row * LDSW + col] = f2bf(v - bf2f(h));
    }
  }
  __syncthreads();

  // ---- layer 2 ----
  mm_pass(4 + cf, lane, phi, plo, hi_ls, lo_ls, acc);
  __syncthreads();
  {
    const int col = 32 * cf + (lane & 31);
    const float bv = b2[col];
    #pragma unroll
    for (int r = 0; r < 16; ++r) {
      int row = (r & 3) + 8 * (r >> 2) + 4 * h5;
      float v = fmaxf(acc[r] + bv, 0.0f);
      unsigned short h = f2bf(v);
      hi_ls[row * LDSW + col] = h;
      lo_ls[row * LDSW + col] = f2bf(v - bf2f(h));
    }
  }
  __syncthreads();

  // ---- LayerNorm (wave handles rows 8cf..8cf+7; lane covers 2 cols) ----
  {
    float g0 = ln_g[2 * lane], g1 = ln_g[2 * lane + 1];
    float be0 = ln_b[2 * lane], be1 = ln_b[2 * lane + 1];
    for (int i = 0; i < 8; ++i) {
      int row = 8 * cf + i;
      unsigned int hp = *(const unsigned int*)&hi_ls[row * LDSW + 2 * lane];
      unsigned int lp = *(const unsigned int*)&lo_ls[row * LDSW + 2 * lane];
      float v0 = bf2f((unsigned short)(hp & 0xffffu)) + bf2f((unsigned short)(lp & 0xffffu));
      float v1 = bf2f((unsigned short)(hp >> 16))     + bf2f((unsigned short)(lp >> 16));
      float s = v0 + v1, q = v0 * v0 + v1 * v1;
      #pragma unroll
      for (int off = 1; off < 64; off <<= 1) {
        s += __shfl_xor(s, off);
        q += __shfl_xor(q, off);
      }
      float mu = s * (1.0f / 128.0f);
      float var = q * (1.0f / 128.0f) - mu * mu;
      float rs = rsqrtf(var + 1e-5f);
      float o0 = (v0 - mu) * rs * g0 + be0;
      float o1 = (v1 - mu) * rs * g1 + be1;
      unsigned short h0 = f2bf(o0), h1 = f2bf(o1);
      unsigned short q0 = f2bf(o0 - bf2f(h0)), q1 = f2bf(o1 - bf2f(h1));
      *(unsigned int*)&hi_ls[row * LDSW + 2 * lane] = (unsigned int)h0 | ((unsigned int)h1 << 16);
      *(unsigned int*)&lo_ls[row * LDSW + 2 * lane] = (unsigned int)q0 | ((unsigned int)q1 << 16);
    }
  }
  __syncthreads();

  // ---- w_lin: 4 head sub-passes, write plain-bf16 xh ----
  for (int hd = 0; hd < 4; ++hd) {
    mm_pass(8 + 4 * hd + cf, lane, phi, plo, hi_ls, lo_ls, acc);
    const int colg = 128 * hd + 32 * cf + (lane & 31);
    #pragma unroll
    for (int r = 0; r < 16; ++r) {
      int row = (r & 3) + 8 * (r >> 2) + 4 * h5;
      xh[(size_t)(row0 + row) * 512 + colg] = f2bf(acc[r]);
    }
  }
}

// ---------------------------------------------------------------------------
// attention coefficients from bf16 xh: one wave per node, lane = 8 channels
// ---------------------------------------------------------------------------
__global__ __launch_bounds__(256) void k_att(
    const unsigned short* __restrict__ xh, const float* __restrict__ att_s,
    const float* __restrict__ att_d, float* __restrict__ a_src,
    float* __restrict__ a_dst)
{
  const int lane = threadIdx.x & 63;
  const int n = blockIdx.x * 4 + (threadIdx.x >> 6);
  uint4 xv = *(const uint4*)&xh[(size_t)n * 512 + 8 * lane];
  const int head = lane >> 4;
  const int cb = 8 * (lane & 15);
  float4 s1 = *(const float4*)&att_s[head * 128 + cb];
  float4 s2 = *(const float4*)&att_s[head * 128 + cb + 4];
  float4 d1 = *(const float4*)&att_d[head * 128 + cb];
  float4 d2 = *(const float4*)&att_d[head * 128 + cb + 4];
  float x0 = BF_LO(xv.x), x1 = BF_HI(xv.x), x2 = BF_LO(xv.y), x3 = BF_HI(xv.y);
  float x4 = BF_LO(xv.z), x5 = BF_HI(xv.z), x6 = BF_LO(xv.w), x7 = BF_HI(xv.w);
  float ps = x0*s1.x + x1*s1.y + x2*s1.z + x3*s1.w + x4*s2.x + x5*s2.y + x6*s2.z + x7*s2.w;
  float pd = x0*d1.x + x1*d1.y + x2*d1.z + x3*d1.w + x4*d2.x + x5*d2.y + x6*d2.z + x7*d2.w;
  #pragma unroll
  for (int off = 1; off < 16; off <<= 1) {
    ps += __shfl_xor(ps, off);
    pd += __shfl_xor(pd, off);
  }
  if ((lane & 15) == 0) {
    a_src[n * 4 + head] = ps;
    a_dst[n * 4 + head] = pd;
  }
}

// ---------------------------------------------------------------------------
// CSR build: histogram -> scan -> scatter (sorted by dst)
// ---------------------------------------------------------------------------
__global__ void k_hist(const int* __restrict__ ei, int* __restrict__ count)
{
  int i = blockIdx.x * 256 + threadIdx.x;
  if (i >= E2T) return;
  int dst = (i < EE) ? ei[EE + i] : (i - EE);
  atomicAdd(&count[dst], 1);
}

__global__ __launch_bounds__(256) void k_scan(const int* __restrict__ count,
                                              int* __restrict__ offsets,
                                              int* __restrict__ cursor)
{
  __shared__ int wtot[4];
  const int t = threadIdx.x;
  const int base = t * (NN / 256);
  int s = 0;
  for (int k = 0; k < NN / 256; ++k) s += count[base + k];
  const int lane = t & 63, w = t >> 6;
  int v = s;
  #pragma unroll
  for (int off = 1; off < 64; off <<= 1) {
    int u = __shfl_up(v, off);
    if (lane >= off) v += u;
  }
  if (lane == 63) wtot[w] = v;
  __syncthreads();
  int wpre = 0;
  for (int i = 0; i < w; ++i) wpre += wtot[i];
  int run = v + wpre - s;
  for (int k = 0; k < NN / 256; ++k) {
    offsets[base + k] = run;
    cursor[base + k] = run;
    run += count[base + k];
  }
  if (t == 255) offsets[NN] = run;
}

__global__ void k_scatter(const int* __restrict__ ei, int* __restrict__ cursor,
                          int* __restrict__ srcs)
{
  int i = blockIdx.x * 256 + threadIdx.x;
  if (i >= E2T) return;
  int s, d;
  if (i < EE) { s = ei[i]; d = ei[EE + i]; }
  else        { s = i - EE; d = s; }
  int pos = atomicAdd(&cursor[d], 1);
  srcs[pos] = s;
}

// ---------------------------------------------------------------------------
// GAT aggregation: one wave per dst node, single pass, bf16 xh gather.
// ---------------------------------------------------------------------------
__global__ __launch_bounds__(256) void k_gat(
    const unsigned short* __restrict__ xh, const float* __restrict__ a_src,
    const float* __restrict__ a_dst, const int* __restrict__ offsets,
    const int* __restrict__ srcs, const float* __restrict__ bias,
    float* __restrict__ out)
{
  __shared__ float ex_ls[4][64][4];
  __shared__ int src_ls[4][64];
  const int lane = threadIdx.x & 63;
  const int w = threadIdx.x >> 6;
  const int n = blockIdx.x * 4 + w;
  const float4 adn = *(const float4*)&a_dst[n * 4];
  const int beg = offsets[n];
  const int deg = offsets[n + 1] - beg;
  const int h1 = lane >> 4;

  float acc[8] = {0, 0, 0, 0, 0, 0, 0, 0};
  float d0 = 0, d1 = 0, d2 = 0, d3 = 0;

  for (int j0 = 0; j0 < deg; j0 += 64) {
    int j = j0 + lane;
    if (j < deg) {
      int s = srcs[beg + j];
      float4 as = *(const float4*)&a_src[s * 4];
      float x0 = __expf(lrelu(as.x + adn.x));
      float x1 = __expf(lrelu(as.y + adn.y));
      float x2 = __expf(lrelu(as.z + adn.z));
      float x3 = __expf(lrelu(as.w + adn.w));
      d0 += x0; d1 += x1; d2 += x2; d3 += x3;
      ex_ls[w][lane][0] = x0; ex_ls[w][lane][1] = x1;
      ex_ls[w][lane][2] = x2; ex_ls[w][lane][3] = x3;
      src_ls[w][lane] = s;
    }
    __builtin_amdgcn_wave_barrier();
    const int cnt = min(64, deg - j0);
    #pragma unroll 4
    for (int jj = 0; jj < cnt; ++jj) {
      int s = src_ls[w][jj];
      float e = ex_ls[w][jj][h1];
      uint4 xv = *(const uint4*)(xh + (size_t)s * 512 + 8 * lane);
      acc[0] = fmaf(e, BF_LO(xv.x), acc[0]);
      acc[1] = fmaf(e, BF_HI(xv.x), acc[1]);
      acc[2] = fmaf(e, BF_LO(xv.y), acc[2]);
      acc[3] = fmaf(e, BF_HI(xv.y), acc[3]);
      acc[4] = fmaf(e, BF_LO(xv.z), acc[4]);
      acc[5] = fmaf(e, BF_HI(xv.z), acc[5]);
      acc[6] = fmaf(e, BF_LO(xv.w), acc[6]);
      acc[7] = fmaf(e, BF_HI(xv.w), acc[7]);
    }
    __builtin_amdgcn_wave_barrier();
  }

  #pragma unroll
  for (int off = 1; off < 64; off <<= 1) {
    d0 += __shfl_xor(d0, off); d1 += __shfl_xor(d1, off);
    d2 += __shfl_xor(d2, off); d3 += __shfl_xor(d3, off);
  }
  float dh = (h1 & 2) ? ((h1 & 1) ? d3 : d2) : ((h1 & 1) ? d1 : d0);
  float inv = 1.0f / (dh + 1e-16f);
  #pragma unroll
  for (int m = 0; m < 8; ++m) {
    float r = acc[m] * inv;
    r += __shfl_xor(r, 16);
    r += __shfl_xor(r, 32);
    acc[m] = r;
  }
  if (lane < 16) {
    const int c0 = 8 * lane;
    float4 o1, o2;
    o1.x = 0.25f * acc[0] + bias[c0 + 0];
    o1.y = 0.25f * acc[1] + bias[c0 + 1];
    o1.z = 0.25f * acc[2] + bias[c0 + 2];
    o1.w = 0.25f * acc[3] + bias[c0 + 3];
    o2.x = 0.25f * acc[4] + bias[c0 + 4];
    o2.y = 0.25f * acc[5] + bias[c0 + 5];
    o2.z = 0.25f * acc[6] + bias[c0 + 6];
    o2.w = 0.25f * acc[7] + bias[c0 + 7];
    *(float4*)&out[(size_t)n * HID + c0]     = o1;
    *(float4*)&out[(size_t)n * HID + c0 + 4] = o2;
  }
}

// ---------------------------------------------------------------------------
extern "C" void kernel_launch(void* const* d_in, const int* in_sizes, int n_in,
                              void* d_out, int out_size, void* d_ws, size_t ws_size,
                              hipStream_t stream)
{
  const float* x     = (const float*)d_in[0];
  const int*   ei    = (const int*)  d_in[1];
  const float* w1    = (const float*)d_in[2];
  const float* b1    = (const float*)d_in[3];
  const float* w2    = (const float*)d_in[4];
  const float* b2    = (const float*)d_in[5];
  const float* ln_g  = (const float*)d_in[6];
  const float* ln_b  = (const float*)d_in[7];
  const float* w_lin = (const float*)d_in[8];
  const float* att_s = (const float*)d_in[9];
  const float* att_d = (const float*)d_in[10];
  const float* bias  = (const float*)d_in[11];
  float* out = (float*)d_out;

  char* ws = (char*)d_ws;
  size_t off = 0;
  auto alloc = [&](size_t bytes) -> char* {
    char* p = ws + off;
    off += (bytes + 255) & ~(size_t)255;
    return p;
  };
  unsigned short* xh  = (unsigned short*)alloc((size_t)NN * 512 * 2);  // 32 MB
  unsigned short* phi = (unsigned short*)alloc(98304 * 2);
  unsigned short* plo = (unsigned short*)alloc(98304 * 2);
  float* a_src  = (float*)alloc((size_t)NN * 4 * 4);
  float* a_dst  = (float*)alloc((size_t)NN * 4 * 4);
  int* count    = (int*)alloc((size_t)NN * 4);
  int* offsets  = (int*)alloc((size_t)(NN + 1) * 4);
  int* cursor   = (int*)alloc((size_t)NN * 4);
  int* srcs     = (int*)alloc((size_t)E2T * 4);
  if (off > ws_size) return;

  hipMemsetAsync(count, 0, (size_t)NN * 4, stream);

  k_pack<<<384, 256, 0, stream>>>(w1, w2, w_lin, phi, plo);
  k_hist<<<(E2T + 255) / 256, 256, 0, stream>>>(ei, count);
  k_scan<<<1, 256, 0, stream>>>(count, offsets, cursor);
  k_fused<<<NN / 32, 256, 0, stream>>>(x, b1, b2, ln_g, ln_b, phi, plo, xh);
  k_scatter<<<(E2T + 255) / 256, 256, 0, stream>>>(ei, cursor, srcs);
  k_att<<<NN / 4, 256, 0, stream>>>(xh, att_s, att_d, a_src, a_dst);
  k_gat<<<NN / 4, 256, 0, stream>>>(xh, a_src, a_dst, offsets, srcs, bias, out);
}